// Round 4
// baseline (474.734 us; speedup 1.0000x reference)
//
#include <hip/hip_runtime.h>

// LIF timestep (SpikeLayer.update_neurons), shape (16,56,56,256) fp32.
// Pure elementwise streaming: 5 inputs read once, 6 outputs written once.
// This revision: 2x float4 per thread per stream -> 10 loads in flight per
// wave (double MLP), half the blocks, nontemporal loads/stores retained.
// Constants: V_THRESH=1.0, DT=1.0, TAU_REFRAC=2.0, TIME=0.5.
// spikes in {0, V_THRESH} so the reference's (spikes < 0) branch is dead.

typedef float f32x4 __attribute__((ext_vector_type(4)));

constexpr float V_THRESH   = 1.0f;
constexpr float TIME_      = 0.5f;
constexpr float REFRAC_SET = TIME_ + 2.0f;  // TIME + TAU_REFRAC = 2.5

__device__ __forceinline__ void lif_step(const f32x4& imp, const f32x4& m,
                                         const f32x4& ma, const f32x4& r,
                                         const f32x4& c,
                                         f32x4& v_spk, f32x4& v_mem, f32x4& v_macc,
                                         f32x4& v_ref, f32x4& v_cnt, f32x4& v_trn) {
#pragma unroll
    for (int k = 0; k < 4; ++k) {
        float mi      = (r[k] > TIME_) ? 0.0f : imp[k];
        float new_mem = m[k] + mi;
        float new_acc = ma[k] + mi;
        bool  fired   = (new_mem >= V_THRESH);
        float spikes  = fired ? V_THRESH : 0.0f;
        v_spk[k]  = spikes;
        v_mem[k]  = fired ? (new_mem - V_THRESH) : new_mem;
        v_macc[k] = new_acc;
        v_ref[k]  = fired ? REFRAC_SET : r[k];
        v_cnt[k]  = c[k] + (fired ? 1.0f : 0.0f);
        v_trn[k]  = spikes * TIME_;
    }
}

__global__ __launch_bounds__(256) void spike_lif_kernel(
    const f32x4* __restrict__ impulse,
    const f32x4* __restrict__ mem,
    const f32x4* __restrict__ mem_acc,
    const f32x4* __restrict__ refrac,
    const f32x4* __restrict__ counts,
    f32x4* __restrict__ out,    // 6 tensors stacked: [spikes, mem, mem_acc, refrac, counts, spiketrain]
    int n4)                     // element count / 4 (even)
{
    int p = blockIdx.x * blockDim.x + threadIdx.x;   // pair index
    long long i = 2LL * p;                           // first float4 of the pair
    if (i + 1 >= n4) return;

    // Issue all 10 loads before any dependent compute (max MLP per wave).
    f32x4 imp0 = __builtin_nontemporal_load(&impulse[i]);
    f32x4 imp1 = __builtin_nontemporal_load(&impulse[i + 1]);
    f32x4 m0   = __builtin_nontemporal_load(&mem[i]);
    f32x4 m1   = __builtin_nontemporal_load(&mem[i + 1]);
    f32x4 ma0  = __builtin_nontemporal_load(&mem_acc[i]);
    f32x4 ma1  = __builtin_nontemporal_load(&mem_acc[i + 1]);
    f32x4 r0   = __builtin_nontemporal_load(&refrac[i]);
    f32x4 r1   = __builtin_nontemporal_load(&refrac[i + 1]);
    f32x4 c0   = __builtin_nontemporal_load(&counts[i]);
    f32x4 c1   = __builtin_nontemporal_load(&counts[i + 1]);

    f32x4 s0, e0, a0, f0, n0, t0;
    f32x4 s1, e1, a1, f1, n1, t1;
    lif_step(imp0, m0, ma0, r0, c0, s0, e0, a0, f0, n0, t0);
    lif_step(imp1, m1, ma1, r1, c1, s1, e1, a1, f1, n1, t1);

    __builtin_nontemporal_store(s0, &out[0LL * n4 + i]);
    __builtin_nontemporal_store(s1, &out[0LL * n4 + i + 1]);
    __builtin_nontemporal_store(e0, &out[1LL * n4 + i]);
    __builtin_nontemporal_store(e1, &out[1LL * n4 + i + 1]);
    __builtin_nontemporal_store(a0, &out[2LL * n4 + i]);
    __builtin_nontemporal_store(a1, &out[2LL * n4 + i + 1]);
    __builtin_nontemporal_store(f0, &out[3LL * n4 + i]);
    __builtin_nontemporal_store(f1, &out[3LL * n4 + i + 1]);
    __builtin_nontemporal_store(n0, &out[4LL * n4 + i]);
    __builtin_nontemporal_store(n1, &out[4LL * n4 + i + 1]);
    __builtin_nontemporal_store(t0, &out[5LL * n4 + i]);
    __builtin_nontemporal_store(t1, &out[5LL * n4 + i + 1]);
}

extern "C" void kernel_launch(void* const* d_in, const int* in_sizes, int n_in,
                              void* d_out, int out_size, void* d_ws, size_t ws_size,
                              hipStream_t stream) {
    const f32x4* impulse = (const f32x4*)d_in[0];
    const f32x4* mem     = (const f32x4*)d_in[1];
    const f32x4* mem_acc = (const f32x4*)d_in[2];
    const f32x4* refrac  = (const f32x4*)d_in[3];
    const f32x4* counts  = (const f32x4*)d_in[4];
    f32x4* out = (f32x4*)d_out;

    const int n     = in_sizes[0];     // 12,845,056 (divisible by 8)
    const int n4    = n / 4;           // 3,211,264 float4 groups
    const int pairs = n4 / 2;          // 1,605,632 float4-pairs
    const int block = 256;
    const int grid  = (pairs + block - 1) / block;   // 6272 blocks

    spike_lif_kernel<<<grid, block, 0, stream>>>(impulse, mem, mem_acc, refrac,
                                                 counts, out, n4);
}